// Round 22
// baseline (125.085 us; speedup 1.0000x reference)
//
#include <hip/hip_runtime.h>

// Fused axial attention (RoadTransformer), bf16 LDS / fp32 compute.
// R22: qr/kr GEMM-ification. R[i][d]=sum_c q[c][i]*rel[c][d], S[j][e]=
//   sum_c k[c][j]*rel[8+c][e] computed per-group on MFMA (K=32 zero-padded),
//   stored f32; P3b becomes 3 gathers + 2 FMA + exp per element (was ~70
//   inst/row of VALU dots + b128 gathers). ONE 1024-thread block per CU
//   (16 waves = SAME 4 waves/SIMD as 2x512, but 149 KB LDS budget; R7's
//   1024-thr failure was the launch_bounds min-waves VGPR spill, not shape).
// Schedule: P3b(g); bar; [w0-3: P4(g) || w4-7: P3a(g+1) || w8-11: R(g+1)
//   || w12-15: S(g+1)]; bar. Single-buffered QKf/R/S (barrier-separated).
// P4 byte-identical to R18/R21. XCD-chunked swizzle, direct stores.

typedef unsigned int u32;
typedef unsigned short u16;
typedef __attribute__((ext_vector_type(8))) short short8;
typedef __attribute__((ext_vector_type(4))) float f32x4;

__device__ __forceinline__ float blo(u32 u) { return __uint_as_float(u << 16); }
__device__ __forceinline__ float bhi(u32 u) { return __uint_as_float(u & 0xffff0000u); }
__device__ __forceinline__ u16 f2bf(float f) {
  const u32 u = __float_as_uint(f);
  return (u16)((u + 0x7fffu + ((u >> 16) & 1u)) >> 16);   // RNE
}
__device__ __forceinline__ u32 pk2(float a, float b) {
  return (u32)f2bf(a) | ((u32)f2bf(b) << 16);
}
__device__ __forceinline__ u32 cvtpk(float lo, float hi) {
  u32 d; asm("v_cvt_pk_bf16_f32 %0, %1, %2" : "=v"(d) : "v"(lo), "v"(hi)); return d;
}

__global__ __launch_bounds__(1024)
void fused_axial(const float* __restrict__ x,
                 const float* __restrict__ w_qkv,
                 const float* __restrict__ rel,
                 const float* __restrict__ bn_qkv,
                 const float* __restrict__ bn_sim,
                 const float* __restrict__ bn_out,
                 float* __restrict__ out) {
  constexpr float EPS = 1e-5f;
  __shared__ __align__(16) u32 SMEM[37336];                // 149344 B -> 1 block/CU, 16 waves
  u16*   const qk_t   = (u16*)SMEM;                        // [64][136]: [h][g*16+c] c<8 q, 8..15 k; 128..135 zeroed
  u16*   const xsb    = (u16*)(SMEM + 4352);               // [64][136] xs staging -> vt[128][68]
  float* const QKf    = (float*)(SMEM + 8704);             // [64][64] f32 qk (per group)
  u16*   const pn     = (u16*)(SMEM + 12800);              // [64][72]  p normal
  u16*   const ps     = (u16*)(SMEM + 15104);              // [64][96]  p skewed (m-tile-local t; K=96 span)
  u16*   const relVm  = (u16*)(SMEM + 18176);              // [16][144]: rel[16+c][t], t<127 else 0
  u16*   const relBqT = (u16*)(SMEM + 19328);              // [128][8]: [d][c]=rel[c][d], d<127 else 0
  u16*   const relBkT = (u16*)(SMEM + 19840);              // [128][8]: [e][c]=rel[8+c][e], e<127 else 0
  float* const Rb     = (float*)(SMEM + 20352);            // [64][132] f32: R[i][d]
  float* const Sb     = (float*)(SMEM + 28800);            // [64][133] f32: S[j][e] (stride 133: bank-clean gather)
  float* const s_sim  = (float*)(SMEM + 37312);            // [24]

  const int bid = blockIdx.x;
  const int b = (bid & 7) * 128 + (bid >> 3);              // XCD-chunked swizzle (1024 % 8 == 0)
  const int n = b >> 6, w = b & 63;
  const int tid = threadIdx.x, wv = tid >> 6, lane = tid & 63;
  const int fq = lane >> 4, fp = lane & 15;                // MFMA lane coords

  // ---- stage inputs ----
  const float* xb = x + n * 524288 + w;                    // x[n][c][h][w]
  for (int idx = tid; idx < 4096; idx += 1024) {
    const int h = idx & 63, cp = idx >> 6;
    const float a0 = xb[(2 * cp) * 4096 + h * 64];
    const float a1 = xb[(2 * cp + 1) * 4096 + h * 64];
    *reinterpret_cast<u32*>(&xsb[h * 136 + 2 * cp]) = pk2(a0, a1);
  }
  if (tid < 512) qk_t[(tid >> 3) * 136 + 128 + (tid & 7)] = 0;  // zero padding cols
  if (tid < 1024) {                                        // relB transposed, 128*8
    const int d = tid >> 3, c = tid & 7;
    relBqT[tid] = (d < 127) ? f2bf(rel[c * 127 + d]) : (u16)0;
    relBkT[tid] = (d < 127) ? f2bf(rel[(8 + c) * 127 + d]) : (u16)0;
  }
  for (int idx = tid; idx < 2304; idx += 1024) {           // 16*144
    const int c = idx / 144, t = idx % 144;
    relVm[idx] = (t < 127) ? f2bf(rel[(16 + c) * 127 + t]) : (u16)0;
  }
  if (tid < 768) {                                         // zero skewed buf ONCE (64*96 u16)
    uint4 z; z.x = 0; z.y = 0; z.z = 0; z.w = 0;
    reinterpret_cast<uint4*>(ps)[tid] = z;
  }
  if (tid < 24) s_sim[tid] = bn_sim[tid] * rsqrtf(bn_sim[72 + tid] + EPS);
  __syncthreads();

  // ---- P1 (MFMA): 16 waves x 1 o-tile. ot=wv: group g1=wv>>1, t=wv&1 ----
  {
    short8 af[4][4];
    #pragma unroll
    for (int ht = 0; ht < 4; ++ht)
      #pragma unroll
      for (int kk = 0; kk < 4; ++kk)
        af[ht][kk] = *reinterpret_cast<const short8*>(&xsb[(ht * 16 + fp) * 136 + kk * 32 + fq * 8]);
    __syncthreads();                                       // xs reads done before vt writes
    u16* vt = xsb;
    const int g1 = wv >> 1, t = wv & 1;
    const int o = wv * 16 + fp;
    short8 bf[4];
    #pragma unroll
    for (int kk = 0; kk < 4; ++kk) {                       // W frag from global f32
      const float* wp = w_qkv + o * 128 + kk * 32 + fq * 8;
      const float4 lo4 = *reinterpret_cast<const float4*>(wp);
      const float4 hi4 = *reinterpret_cast<const float4*>(wp + 4);
      union { u32 u[4]; short8 s; } uu;
      uu.u[0] = cvtpk(lo4.x, lo4.y); uu.u[1] = cvtpk(lo4.z, lo4.w);
      uu.u[2] = cvtpk(hi4.x, hi4.y); uu.u[3] = cvtpk(hi4.z, hi4.w);
      bf[kk] = uu.s;
    }
    const float ga = bn_qkv[o], be = bn_qkv[256 + o], mu = bn_qkv[512 + o], va = bn_qkv[768 + o];
    const float sq = ga * rsqrtf(va + EPS), tq = be - mu * sq;
    #pragma unroll
    for (int ht = 0; ht < 4; ++ht) {
      f32x4 acc = {0.f, 0.f, 0.f, 0.f};
      #pragma unroll
      for (int kk = 0; kk < 4; ++kk)
        acc = __builtin_amdgcn_mfma_f32_16x16x32_bf16(af[ht][kk], bf[kk], acc, 0, 0, 0);
      u16 e[4];
      #pragma unroll
      for (int r = 0; r < 4; ++r) e[r] = f2bf(sq * acc[r] + tq);
      if (t == 0) {
        #pragma unroll
        for (int r = 0; r < 4; ++r)
          qk_t[(ht * 16 + fq * 4 + r) * 136 + g1 * 16 + fp] = e[r];
      } else {
        uint2 pr;
        pr.x = (u32)e[0] | ((u32)e[1] << 16);
        pr.y = (u32)e[2] | ((u32)e[3] << 16);
        *reinterpret_cast<uint2*>(&vt[(g1 * 16 + fp) * 68 + ht * 16 + 4 * fq]) = pr;
      }
    }
  }
  __syncthreads();

  const u16* const vt = xsb;
  short8 zero8;
  { zero8[0]=0; zero8[1]=0; zero8[2]=0; zero8[3]=0; zero8[4]=0; zero8[5]=0; zero8[6]=0; zero8[7]=0; }
  short8 onev;
  { const short o1 = (short)0x3F80;                        // bf16 1.0
    onev[0]=o1; onev[1]=o1; onev[2]=o1; onev[3]=o1; onev[4]=o1; onev[5]=o1; onev[6]=o1; onev[7]=o1; }

  // PREP(GC): waves 4-7 P3a, 8-11 R, 12-15 S for the group with column base GC.
  // A-tail overruns (cols >= 136) land in qk_t/xsb rows = finite bf16, x0 = 0.
#define PREP(GC)                                                                          \
  if (wv < 8) {                                                                           \
    const int it = wv - 4;                                                                \
    const short8 af = *reinterpret_cast<const short8*>(&qk_t[(it * 16 + fp) * 136 + (GC) + fq * 8]); \
    _Pragma("unroll")                                                                     \
    for (int jt = 0; jt < 4; ++jt) {                                                      \
      const short8 bk = *reinterpret_cast<const short8*>(&qk_t[(jt * 16 + fp) * 136 + (GC) + 8]); \
      const short8 bfz = (fq == 0) ? bk : zero8;                                          \
      f32x4 d = {0.f, 0.f, 0.f, 0.f};                                                     \
      d = __builtin_amdgcn_mfma_f32_16x16x32_bf16(af, bfz, d, 0, 0, 0);                   \
      _Pragma("unroll")                                                                   \
      for (int r = 0; r < 4; ++r)                                                         \
        QKf[(it * 16 + 4 * fq + r) * 64 + jt * 16 + fp] = d[r];                           \
    }                                                                                     \
  } else if (wv < 12) {                                                                   \
    const int mt = wv - 8;                                                                \
    const short8 aR = *reinterpret_cast<const short8*>(&qk_t[(mt * 16 + fp) * 136 + (GC) + fq * 8]); \
    _Pragma("unroll")                                                                     \
    for (int nt = 0; nt < 8; ++nt) {                                                      \
      const short8 bq = *reinterpret_cast<const short8*>(&relBqT[(nt * 16 + fp) * 8]);    \
      const short8 bfz = (fq == 0) ? bq : zero8;                                          \
      f32x4 d = {0.f, 0.f, 0.f, 0.f};                                                     \
      d = __builtin_amdgcn_mfma_f32_16x16x32_bf16(aR, bfz, d, 0, 0, 0);                   \
      _Pragma("unroll")                                                                   \
      for (int r = 0; r < 4; ++r)                                                         \
        Rb[(mt * 16 + 4 * fq + r) * 132 + nt * 16 + fp] = d[r];                           \
    }                                                                                     \
  } else {                                                                                \
    const int mt = wv - 12;                                                               \
    const short8 aS = *reinterpret_cast<const short8*>(&qk_t[(mt * 16 + fp) * 136 + (GC) + 8 + fq * 8]); \
    _Pragma("unroll")                                                                     \
    for (int nt = 0; nt < 8; ++nt) {                                                      \
      const short8 bk2 = *reinterpret_cast<const short8*>(&relBkT[(nt * 16 + fp) * 8]);   \
      const short8 bfz = (fq == 0) ? bk2 : zero8;                                         \
      f32x4 d = {0.f, 0.f, 0.f, 0.f};                                                     \
      d = __builtin_amdgcn_mfma_f32_16x16x32_bf16(aS, bfz, d, 0, 0, 0);                   \
      _Pragma("unroll")                                                                   \
      for (int r = 0; r < 4; ++r)                                                         \
        Sb[(mt * 16 + 4 * fq + r) * 133 + nt * 16 + fp] = d[r];                           \
    }                                                                                     \
  }

  // ---- prologue: prep group 0 (waves 4-15; waves 0-3 idle once) ----
  if (wv >= 4) { PREP(0) }
  __syncthreads();

  for (int g = 0; g < 8; ++g) {
    const int gc = g * 16;

    // ---- P3b(g): logits + exp; 16 waves x 4 rows; pure gathers + 2 FMA ----
    {
      const float sqk = s_sim[g], sqr = s_sim[8 + g], skr = s_sim[16 + g];
      const int i0 = wv * 4;
      #pragma unroll
      for (int r = 0; r < 4; ++r) {
        const int i = i0 + r;
        const float qk = QKf[i * 64 + lane];
        const float rv = Rb[i * 132 + (i - lane + 63)];
        const float sg = Sb[lane * 133 + (lane - i + 63)];
        const float logit = fmaf(sqk, qk, fmaf(sqr, rv, skr * sg));
        const u16 eb = f2bf(__expf(logit));
        pn[i * 72 + lane] = eb;
        ps[i * 96 + (i & 15) + 63 - lane] = eb;
      }
    }
    __syncthreads();

    // ---- Phase A: w0-3 P4(g); w4-15 prep(g+1) ----
    if (wv < 4) {
      const int mt = wv;
      const u16* pnb = &pn[(mt * 16 + fp) * 72];
      const u16* psb = &ps[(mt * 16 + fp) * 96];
      const u16* vtb = vt + (gc + fp) * 68;                // v-channel fp of group g
      const short8 an0 = *reinterpret_cast<const short8*>(&pnb[fq * 8]);
      const short8 an1 = *reinterpret_cast<const short8*>(&pnb[32 + fq * 8]);
      f32x4 sv = {0.f, 0.f, 0.f, 0.f}, se = sv, psm = sv;
      {
        union { u32 u[4]; short8 s; } v0, v1;
        const uint2 t0 = *reinterpret_cast<const uint2*>(&vtb[fq * 8]);
        const uint2 t1 = *reinterpret_cast<const uint2*>(&vtb[fq * 8 + 4]);
        v0.u[0] = t0.x; v0.u[1] = t0.y; v0.u[2] = t1.x; v0.u[3] = t1.y;
        const uint2 t2 = *reinterpret_cast<const uint2*>(&vtb[32 + fq * 8]);
        const uint2 t3 = *reinterpret_cast<const uint2*>(&vtb[32 + fq * 8 + 4]);
        v1.u[0] = t2.x; v1.u[1] = t2.y; v1.u[2] = t3.x; v1.u[3] = t3.y;
        sv = __builtin_amdgcn_mfma_f32_16x16x32_bf16(an0, v0.s, sv, 0, 0, 0);
        sv = __builtin_amdgcn_mfma_f32_16x16x32_bf16(an1, v1.s, sv, 0, 0, 0);
      }
      psm = __builtin_amdgcn_mfma_f32_16x16x32_bf16(an0, onev, psm, 0, 0, 0);
      psm = __builtin_amdgcn_mfma_f32_16x16x32_bf16(an1, onev, psm, 0, 0, 0);
      #pragma unroll
      for (int kk = 0; kk < 3; ++kk) {                     // K=96 m-tile-local skew
        const short8 as = *reinterpret_cast<const short8*>(&psb[kk * 32 + fq * 8]);
        const short8 br = *reinterpret_cast<const short8*>(&relVm[fp * 144 + mt * 16 + kk * 32 + fq * 8]);
        se = __builtin_amdgcn_mfma_f32_16x16x32_bf16(as, br, se, 0, 0, 0);
      }
      const int P = gc + fp;
      const float2 ga2 = *reinterpret_cast<const float2*>(&bn_out[2 * P]);
      const float2 be2 = *reinterpret_cast<const float2*>(&bn_out[256 + 2 * P]);
      const float2 mu2 = *reinterpret_cast<const float2*>(&bn_out[512 + 2 * P]);
      const float2 va2 = *reinterpret_cast<const float2*>(&bn_out[768 + 2 * P]);
      const float so0 = ga2.x * rsqrtf(va2.x + EPS), to0 = be2.x - mu2.x * so0;
      const float so1 = ga2.y * rsqrtf(va2.y + EPS), to1 = be2.y - mu2.y * so1;
      #pragma unroll
      for (int r = 0; r < 4; ++r) {
        const float inv = 1.0f / psm[r];
        const int i = mt * 16 + 4 * fq + r;
        out[(n * 128 + P) * 4096 + i * 64 + w] =
            fmaf(so0, sv[r] * inv, to0) + fmaf(so1, se[r] * inv, to1);
      }
    } else if (g < 7) {
      PREP(gc + 16)
    }
    __syncthreads();
  }
#undef PREP
}

extern "C" void kernel_launch(void* const* d_in, const int* in_sizes, int n_in,
                              void* d_out, int out_size, void* d_ws, size_t ws_size,
                              hipStream_t stream) {
  const float* x      = (const float*)d_in[0];
  const float* w_qkv  = (const float*)d_in[1];
  const float* rel    = (const float*)d_in[2];
  const float* bn_qkv = (const float*)d_in[3];
  const float* bn_sim = (const float*)d_in[4];
  const float* bn_out = (const float*)d_in[5];
  float* out = (float*)d_out;
  fused_axial<<<1024, 1024, 0, stream>>>(x, w_qkv, rel, bn_qkv, bn_sim, bn_out, out);
}

// Round 23
// 104.237 us; speedup vs baseline: 1.2000x; 1.2000x over previous
//
#include <hip/hip_runtime.h>

// Fused axial attention (RoadTransformer), bf16 LDS / fp32 compute.
// R23 = FINAL: revert to R21/R18 (best measured: 104.3-104.4us, reproduced).
// R22's qr/kr GEMM-ification (1 blk/CU, 149KB LDS) regressed to 125us:
// eliminating P3b's VALU work lost the 2-blocks/CU barrier-stall overlap,
// proving the kernel is phase-serialization-bound, not ALU-bound.
// Structure: P1 qkv GEMM on MFMA; P3a qk on MFMA (K=32, zero-padded B);
// P3b logits+exp on VALU (batch-issued loads); P4 sv/sve/psum on MFMA
// (skewed-p trick); pipelined [P4(g) || P3a(g+1)] phase.
// 512 thr, 2 blocks/CU (81472 B LDS), XCD-chunked swizzle, direct stores.

typedef unsigned int u32;
typedef unsigned short u16;
typedef __attribute__((ext_vector_type(8))) short short8;
typedef __attribute__((ext_vector_type(4))) float f32x4;

__device__ __forceinline__ float blo(u32 u) { return __uint_as_float(u << 16); }
__device__ __forceinline__ float bhi(u32 u) { return __uint_as_float(u & 0xffff0000u); }
__device__ __forceinline__ u16 f2bf(float f) {
  const u32 u = __float_as_uint(f);
  return (u16)((u + 0x7fffu + ((u >> 16) & 1u)) >> 16);   // RNE
}
__device__ __forceinline__ u32 pk2(float a, float b) {
  return (u32)f2bf(a) | ((u32)f2bf(b) << 16);
}
__device__ __forceinline__ u32 cvtpk(float lo, float hi) {
  u32 d; asm("v_cvt_pk_bf16_f32 %0, %1, %2" : "=v"(d) : "v"(lo), "v"(hi)); return d;
}
#define UNPK(u4, f) { f[0]=blo((u4).x); f[1]=bhi((u4).x); f[2]=blo((u4).y); f[3]=bhi((u4).y); \
                      f[4]=blo((u4).z); f[5]=bhi((u4).z); f[6]=blo((u4).w); f[7]=bhi((u4).w); }

__global__ __launch_bounds__(512, 2)
void fused_axial(const float* __restrict__ x,
                 const float* __restrict__ w_qkv,
                 const float* __restrict__ rel,
                 const float* __restrict__ bn_qkv,
                 const float* __restrict__ bn_sim,
                 const float* __restrict__ bn_out,
                 float* __restrict__ out) {
  constexpr float EPS = 1e-5f;
  __shared__ __align__(16) u32 SMEM[20368];                // 81472 B -> 2 blocks/CU
  u16*   const qk_t  = (u16*)SMEM;                         // [64][136]: [h][g*16+c] c<8 q, 8..15 k; 128..135 zeroed
  u16*   const xsb   = (u16*)(SMEM + 4352);                // [64][136] xs staging -> vt[128][68]
  float* const QKf   = (float*)(SMEM + 8704);              // [64][64] f32 QK (per group)
  u16*   const pn    = (u16*)(SMEM + 12800);               // [64][72]  p normal
  u16*   const ps    = (u16*)(SMEM + 15104);               // [64][96]  p skewed (m-tile-local t; K=96 read span)
  u16*   const relCf = (u16*)(SMEM + 18176);               // [127][16]: c<8 rel[c][d]; 8..15 rel[c][126-d]
  u16*   const relVm = (u16*)(SMEM + 19192);               // [16][144]: rel[16+c][t], t<127 else 0
  float* const s_sim = (float*)(SMEM + 20344);             // [24]

  const int bid = blockIdx.x;
  const int b = (bid & 7) * 128 + (bid >> 3);              // XCD-chunked swizzle (1024 % 8 == 0)
  const int n = b >> 6, w = b & 63;
  const int tid = threadIdx.x, wv = tid >> 6, lane = tid & 63;
  const int fq = lane >> 4, fp = lane & 15;                // MFMA lane coords

  // ---- stage inputs ----
  const float* xb = x + n * 524288 + w;                    // x[n][c][h][w]
  for (int idx = tid; idx < 4096; idx += 512) {
    const int h = idx & 63, cp = idx >> 6;
    const float a0 = xb[(2 * cp) * 4096 + h * 64];
    const float a1 = xb[(2 * cp + 1) * 4096 + h * 64];
    *reinterpret_cast<u32*>(&xsb[h * 136 + 2 * cp]) = pk2(a0, a1);
  }
  if (tid < 512) qk_t[(tid >> 3) * 136 + 128 + (tid & 7)] = 0;  // zero padding cols
  for (int idx = tid; idx < 2032; idx += 512) {            // 127*16
    const int d = idx >> 4, c = idx & 15;
    relCf[d * 16 + c] = f2bf(rel[c * 127 + ((c >= 8) ? (126 - d) : d)]);
  }
  for (int idx = tid; idx < 2304; idx += 512) {            // 16*144
    const int c = idx / 144, t = idx % 144;
    relVm[idx] = (t < 127) ? f2bf(rel[(16 + c) * 127 + t]) : (u16)0;
  }
  {
    uint4 z; z.x = 0; z.y = 0; z.z = 0; z.w = 0;
    uint4* pz = reinterpret_cast<uint4*>(ps);
    for (int idx = tid; idx < 768; idx += 512) pz[idx] = z; // zero skewed buf ONCE (64*96 u16)
  }
  if (tid < 24) s_sim[tid] = bn_sim[tid] * rsqrtf(bn_sim[72 + tid] + EPS);
  __syncthreads();

  // ---- P1 (MFMA): qk_t[h][g*16+c] (t=0 tiles), vt[g*16+c][j] stride 68 (t=1) ----
  {
    short8 af[4][4];
    #pragma unroll
    for (int ht = 0; ht < 4; ++ht)
      #pragma unroll
      for (int kk = 0; kk < 4; ++kk)
        af[ht][kk] = *reinterpret_cast<const short8*>(&xsb[(ht * 16 + fp) * 136 + kk * 32 + fq * 8]);
    __syncthreads();                                       // xs reads done before vt writes
    u16* vt = xsb;
    #pragma unroll
    for (int t = 0; t < 2; ++t) {
      const int o = (wv * 2 + t) * 16 + fp;                // t=0: q,k of group wv; t=1: v
      short8 bf[4];
      #pragma unroll
      for (int kk = 0; kk < 4; ++kk) {                     // W frag from global f32
        const float* wp = w_qkv + o * 128 + kk * 32 + fq * 8;
        const float4 lo4 = *reinterpret_cast<const float4*>(wp);
        const float4 hi4 = *reinterpret_cast<const float4*>(wp + 4);
        union { u32 u[4]; short8 s; } uu;
        uu.u[0] = cvtpk(lo4.x, lo4.y); uu.u[1] = cvtpk(lo4.z, lo4.w);
        uu.u[2] = cvtpk(hi4.x, hi4.y); uu.u[3] = cvtpk(hi4.z, hi4.w);
        bf[kk] = uu.s;
      }
      const float ga = bn_qkv[o], be = bn_qkv[256 + o], mu = bn_qkv[512 + o], va = bn_qkv[768 + o];
      const float sq = ga * rsqrtf(va + EPS), tq = be - mu * sq;
      #pragma unroll
      for (int ht = 0; ht < 4; ++ht) {
        f32x4 acc = {0.f, 0.f, 0.f, 0.f};
        #pragma unroll
        for (int kk = 0; kk < 4; ++kk)
          acc = __builtin_amdgcn_mfma_f32_16x16x32_bf16(af[ht][kk], bf[kk], acc, 0, 0, 0);
        u16 e[4];
        #pragma unroll
        for (int r = 0; r < 4; ++r) e[r] = f2bf(sq * acc[r] + tq);
        if (t == 0) {
          #pragma unroll
          for (int r = 0; r < 4; ++r)
            qk_t[(ht * 16 + fq * 4 + r) * 136 + wv * 16 + fp] = e[r];
        } else {
          uint2 pr;
          pr.x = (u32)e[0] | ((u32)e[1] << 16);
          pr.y = (u32)e[2] | ((u32)e[3] << 16);
          *reinterpret_cast<uint2*>(&vt[(wv * 16 + fp) * 68 + ht * 16 + 4 * fq]) = pr;
        }
      }
    }
  }
  __syncthreads();

  const u16* const vt = xsb;
  short8 zero8;
  { zero8[0]=0; zero8[1]=0; zero8[2]=0; zero8[3]=0; zero8[4]=0; zero8[5]=0; zero8[6]=0; zero8[7]=0; }
  short8 onev;
  { const short o1 = (short)0x3F80;                        // bf16 1.0
    onev[0]=o1; onev[1]=o1; onev[2]=o1; onev[3]=o1; onev[4]=o1; onev[5]=o1; onev[6]=o1; onev[7]=o1; }

  // ---- prologue: P3a(0), all 8 waves (it = wv>>1, jt = (wv&1)*2 + {0,1}) ----
  {
    const int it = wv >> 1;
    const short8 af = *reinterpret_cast<const short8*>(&qk_t[(it * 16 + fp) * 136 + fq * 8]);
    #pragma unroll
    for (int jj = 0; jj < 2; ++jj) {
      const int jt = (wv & 1) * 2 + jj;
      const short8 bk = *reinterpret_cast<const short8*>(&qk_t[(jt * 16 + fp) * 136 + 8]);
      const short8 bf = (fq == 0) ? bk : zero8;            // K=8 real, rest zero
      f32x4 d = {0.f, 0.f, 0.f, 0.f};
      d = __builtin_amdgcn_mfma_f32_16x16x32_bf16(af, bf, d, 0, 0, 0);
      #pragma unroll
      for (int r = 0; r < 4; ++r)
        QKf[(it * 16 + 4 * fq + r) * 64 + jt * 16 + fp] = d[r];
    }
  }
  __syncthreads();

  for (int g = 0; g < 8; ++g) {
    const int gc = g * 16;

    // ---- P3b(g): logits + exp; wave wv -> rows wv*8..+7; batch-issued loads ----
    {
      const float sqk = s_sim[g], sqr = s_sim[8 + g], skr = s_sim[16 + g];
      const uint4 ku = *reinterpret_cast<const uint4*>(&qk_t[lane * 136 + gc + 8]);
      float kf[8]; UNPK(ku, kf);
      const int i0 = wv * 8;
      const int d0 = i0 - lane + 63;                       // d for row r is d0 + r (0..126)
      float qk8[8];
      uint4 qu8[8];
      #pragma unroll
      for (int r = 0; r < 8; ++r) {
        qk8[r] = QKf[(i0 + r) * 64 + lane];
        qu8[r] = *reinterpret_cast<const uint4*>(&qk_t[(i0 + r) * 136 + gc]);
      }
      uint4 r1n = *reinterpret_cast<const uint4*>(&relCf[d0 * 16]);
      uint4 r2n = *reinterpret_cast<const uint4*>(&relCf[d0 * 16 + 8]);
      #pragma unroll
      for (int r = 0; r < 8; ++r) {
        const uint4 r1c = r1n, r2c = r2n;
        if (r < 7) {
          const int dn = d0 + r + 1;
          r1n = *reinterpret_cast<const uint4*>(&relCf[dn * 16]);
          r2n = *reinterpret_cast<const uint4*>(&relCf[dn * 16 + 8]);
        }
        const int i = i0 + r;
        float qf[8], ra[8], rb[8];
        UNPK(qu8[r], qf); UNPK(r1c, ra); UNPK(r2c, rb);
        float qr = 0.f, kr = 0.f;
        #pragma unroll
        for (int c = 0; c < 8; ++c) {
          qr = fmaf(qf[c], ra[c], qr);
          kr = fmaf(kf[c], rb[c], kr);
        }
        const float logit = fmaf(sqk, qk8[r], fmaf(sqr, qr, skr * kr));
        const u16 eb = f2bf(__expf(logit));
        pn[i * 72 + lane] = eb;
        ps[i * 96 + (i & 15) + 63 - lane] = eb;
      }
    }
    __syncthreads();

    // ---- Phase A: waves 0-3 -> P4(g);  waves 4-7 -> P3a(g+1) ----
    if (wv < 4) {
      const int mt = wv;
      const u16* pnb = &pn[(mt * 16 + fp) * 72];
      const u16* psb = &ps[(mt * 16 + fp) * 96];
      const u16* vtb = vt + (gc + fp) * 68;                // v-channel fp of group g
      const short8 an0 = *reinterpret_cast<const short8*>(&pnb[fq * 8]);
      const short8 an1 = *reinterpret_cast<const short8*>(&pnb[32 + fq * 8]);
      f32x4 sv = {0.f, 0.f, 0.f, 0.f}, se = sv, psm = sv;
      {
        union { u32 u[4]; short8 s; } v0, v1;
        const uint2 t0 = *reinterpret_cast<const uint2*>(&vtb[fq * 8]);
        const uint2 t1 = *reinterpret_cast<const uint2*>(&vtb[fq * 8 + 4]);
        v0.u[0] = t0.x; v0.u[1] = t0.y; v0.u[2] = t1.x; v0.u[3] = t1.y;
        const uint2 t2 = *reinterpret_cast<const uint2*>(&vtb[32 + fq * 8]);
        const uint2 t3 = *reinterpret_cast<const uint2*>(&vtb[32 + fq * 8 + 4]);
        v1.u[0] = t2.x; v1.u[1] = t2.y; v1.u[2] = t3.x; v1.u[3] = t3.y;
        sv = __builtin_amdgcn_mfma_f32_16x16x32_bf16(an0, v0.s, sv, 0, 0, 0);
        sv = __builtin_amdgcn_mfma_f32_16x16x32_bf16(an1, v1.s, sv, 0, 0, 0);
      }
      psm = __builtin_amdgcn_mfma_f32_16x16x32_bf16(an0, onev, psm, 0, 0, 0);
      psm = __builtin_amdgcn_mfma_f32_16x16x32_bf16(an1, onev, psm, 0, 0, 0);
      #pragma unroll
      for (int kk = 0; kk < 3; ++kk) {                     // K=96 m-tile-local skew (full span valid)
        const short8 as = *reinterpret_cast<const short8*>(&psb[kk * 32 + fq * 8]);
        const short8 br = *reinterpret_cast<const short8*>(&relVm[fp * 144 + mt * 16 + kk * 32 + fq * 8]);
        se = __builtin_amdgcn_mfma_f32_16x16x32_bf16(as, br, se, 0, 0, 0);
      }
      const int P = gc + fp;
      const float2 ga2 = *reinterpret_cast<const float2*>(&bn_out[2 * P]);
      const float2 be2 = *reinterpret_cast<const float2*>(&bn_out[256 + 2 * P]);
      const float2 mu2 = *reinterpret_cast<const float2*>(&bn_out[512 + 2 * P]);
      const float2 va2 = *reinterpret_cast<const float2*>(&bn_out[768 + 2 * P]);
      const float so0 = ga2.x * rsqrtf(va2.x + EPS), to0 = be2.x - mu2.x * so0;
      const float so1 = ga2.y * rsqrtf(va2.y + EPS), to1 = be2.y - mu2.y * so1;
      #pragma unroll
      for (int r = 0; r < 4; ++r) {
        const float inv = 1.0f / psm[r];
        const int i = mt * 16 + 4 * fq + r;
        out[(n * 128 + P) * 4096 + i * 64 + w] =
            fmaf(so0, sv[r] * inv, to0) + fmaf(so1, se[r] * inv, to1);
      }
    } else if (g < 7) {
      // P3a(g+1): 4 waves, it = wv-4, jt = 0..3
      const int g2c = gc + 16;
      const int it = wv - 4;
      const short8 af = *reinterpret_cast<const short8*>(&qk_t[(it * 16 + fp) * 136 + g2c + fq * 8]);
      #pragma unroll
      for (int jt = 0; jt < 4; ++jt) {
        const short8 bk = *reinterpret_cast<const short8*>(&qk_t[(jt * 16 + fp) * 136 + g2c + 8]);
        const short8 bf = (fq == 0) ? bk : zero8;          // K=8 real, rest zero
        f32x4 d = {0.f, 0.f, 0.f, 0.f};
        d = __builtin_amdgcn_mfma_f32_16x16x32_bf16(af, bf, d, 0, 0, 0);
        #pragma unroll
        for (int r = 0; r < 4; ++r)
          QKf[(it * 16 + 4 * fq + r) * 64 + jt * 16 + fp] = d[r];
      }
    }
    __syncthreads();
  }
}

extern "C" void kernel_launch(void* const* d_in, const int* in_sizes, int n_in,
                              void* d_out, int out_size, void* d_ws, size_t ws_size,
                              hipStream_t stream) {
  const float* x      = (const float*)d_in[0];
  const float* w_qkv  = (const float*)d_in[1];
  const float* rel    = (const float*)d_in[2];
  const float* bn_qkv = (const float*)d_in[3];
  const float* bn_sim = (const float*)d_in[4];
  const float* bn_out = (const float*)d_in[5];
  float* out = (float*)d_out;
  fused_axial<<<1024, 512, 0, stream>>>(x, w_qkv, rel, bn_qkv, bn_sim, bn_out, out);
}